// Round 4
// baseline (1787.586 us; speedup 1.0000x reference)
//
#include <hip/hip_runtime.h>

typedef float f32x4 __attribute__((ext_vector_type(4)));
typedef float f32x2 __attribute__((ext_vector_type(2)));
typedef short s16x8 __attribute__((ext_vector_type(8)));
typedef __bf16 bf16x8 __attribute__((ext_vector_type(8)));

__device__ __forceinline__ unsigned short f2bf(float f) {
    unsigned int u = __builtin_bit_cast(unsigned int, f);
    u += 0x7FFFu + ((u >> 16) & 1u);
    return (unsigned short)(u >> 16);
}

__device__ __forceinline__ f32x4 MFMA(s16x8 a, s16x8 b, f32x4 c) {
    return __builtin_amdgcn_mfma_f32_16x16x32_bf16(
        __builtin_bit_cast(bf16x8, a), __builtin_bit_cast(bf16x8, b), c, 0, 0, 0);
}

__device__ __forceinline__ float sigm(float v) {
    return __builtin_amdgcn_rcpf(1.f + __builtin_amdgcn_exp2f(-1.4426950408889634f * v));
}
__device__ __forceinline__ float tanh_(float v) {
    return 2.f * __builtin_amdgcn_rcpf(1.f + __builtin_amdgcn_exp2f(-2.8853900817779268f * v)) - 1.f;
}

// ---------------- prologue kernels ----------------

// WC[j,f] = sum_e Wih1[j,e] * W_enc[e,f]; benc[j] = sum_e Wih1[j,e] * b_enc[e]
__global__ void wc_kernel(const float* __restrict__ Wih1, const float* __restrict__ W_enc,
                          const float* __restrict__ b_enc, float* __restrict__ WC,
                          float* __restrict__ benc) {
    int i = blockIdx.x * 256 + threadIdx.x;
    if (i >= 1024 * 35) return;
    int j = i / 35;
    int f = i - j * 35;
    const float* wr = Wih1 + j * 256;
    float s = 0.f;
    if (f < 34) {
        for (int e = 0; e < 256; ++e) s += wr[e] * W_enc[e * 34 + f];
        WC[j * 34 + f] = s;
    } else {
        for (int e = 0; e < 256; ++e) s += wr[e] * b_enc[e];
        benc[j] = s;
    }
}

// Pack W (row-major [srcRows, srcK]) into per-wave-sequential bf16 B-frag streams:
// linear s16x8 index ((ntb*KK + kk)*G + g)*64 + lane holds
//   W[g*gStride + ntb*16 + (lane&15)][kk*32 + (lane>>4)*8 + j]  (0 outside bounds)
__global__ void pack_kernel(const float* __restrict__ src, unsigned short* __restrict__ dst,
                            int NTB, int KK, int G, int gStride, int srcRows, int srcK) {
    int idx = blockIdx.x * 256 + threadIdx.x;
    int total = NTB * KK * G * 64;
    if (idx >= total) return;
    int lane = idx & 63, q = idx >> 6;
    int g = q % G; q /= G;
    int kk = q % KK;
    int ntb = q / KK;
    int row = g * gStride + ntb * 16 + (lane & 15);
    int kbase = kk * 32 + ((lane >> 4) & 3) * 8;
    s16x8 v;
    #pragma unroll
    for (int j = 0; j < 8; ++j) {
        int k = kbase + j;
        float fv = (row < srcRows && k < srcK) ? src[row * srcK + k] : 0.f;
        v[j] = (short)f2bf(fv);
    }
    *(s16x8*)(dst + (long)idx * 8) = v;
}

__global__ void bias_kernel(const float* bih1, const float* bhh1, const float* benc,
                            const float* bih2, const float* bhh2, const float* b_dec,
                            float* bs1a, float* bs1b, float* bs2, float* bdec) {
    int j = blockIdx.x * 256 + threadIdx.x;
    if (j < 1024) {
        float s = bih1[j] + bhh1[j];
        bs1a[j] = s + benc[j];
        bs1b[j] = s;
        bs2[j] = bih2[j] + bhh2[j];
    }
    if (j < 48) bdec[j] = (j < 34) ? b_dec[j] : 0.f;
}

// ---------------- fused LSTM kernel ----------------

// One LSTM cell over this block's 64 rows. Fully unrolled K-stream (input phase
// KKIN ktiles of 32, then hidden phase 8 ktiles) with depth-2 A/B register
// ping-pong; all addresses are base+immediate under full unroll.
// Writes new h (bf16) directly into Hout (the inactive double-buffer) — no reader
// of Hout exists during this cell, so only ONE barrier (at end) is needed.
template<int KKIN, int SIN>
__device__ __forceinline__ void cell_step(
    const unsigned short* __restrict__ Ain,    // LDS, input-phase A, stride SIN shorts
    const unsigned short* __restrict__ Ahid,   // LDS, hidden-phase A, stride 260 shorts
    const s16x8* __restrict__ pWin,            // packed weights, KK=KKIN
    const s16x8* __restrict__ pWhid,           // packed weights, KK=8
    const float (&bias)[2][4],
    float (&cst)[2][4][4],
    unsigned short* __restrict__ Hout,         // LDS, stride 260 shorts
    int wave, int lane, int ln15, int quad)
{
    const int aIn   = ln15 * SIN + quad * 8;
    const int aHid  = ln15 * 260 + quad * 8;
    const int hbase = (quad * 4) * 260 + wave * 32 + ln15;
    #pragma unroll
    for (int s = 0; s < 2; ++s) {
        const int ntb = wave * 2 + s;
        const s16x8* wIn  = pWin  + __builtin_amdgcn_readfirstlane(ntb * (KKIN * 256));
        const s16x8* wHid = pWhid + __builtin_amdgcn_readfirstlane(ntb * 2048);
        f32x4 acc[4][4];
        #pragma unroll
        for (int g = 0; g < 4; ++g) {
            const float b = bias[s][g];
            #pragma unroll
            for (int mt = 0; mt < 4; ++mt) acc[g][mt] = f32x4{b, b, b, b};
        }
        constexpr int TOT = KKIN + 8;
        s16x8 A[2][4], B[2][4];
        #pragma unroll
        for (int g = 0; g < 4; ++g) B[0][g] = wIn[lane + g * 64];
        #pragma unroll
        for (int mt = 0; mt < 4; ++mt) A[0][mt] = *(const s16x8*)(Ain + aIn + mt * (16 * SIN));
        #pragma unroll
        for (int u = 0; u < TOT; ++u) {
            const int cur = u & 1, nxt = cur ^ 1;
            if (u + 1 < TOT) {
                const int v = u + 1;
                if (v < KKIN) {
                    #pragma unroll
                    for (int g = 0; g < 4; ++g) B[nxt][g] = wIn[lane + v * 256 + g * 64];
                    #pragma unroll
                    for (int mt = 0; mt < 4; ++mt)
                        A[nxt][mt] = *(const s16x8*)(Ain + aIn + v * 32 + mt * (16 * SIN));
                } else {
                    const int vh = v - KKIN;
                    #pragma unroll
                    for (int g = 0; g < 4; ++g) B[nxt][g] = wHid[lane + vh * 256 + g * 64];
                    #pragma unroll
                    for (int mt = 0; mt < 4; ++mt)
                        A[nxt][mt] = *(const s16x8*)(Ahid + aHid + vh * 32 + mt * (16 * 260));
                }
            }
            #pragma unroll
            for (int g = 0; g < 4; ++g)
                #pragma unroll
                for (int mt = 0; mt < 4; ++mt)
                    acc[g][mt] = MFMA(A[cur][mt], B[cur][g], acc[g][mt]);
        }
        // activations; write h straight to the inactive buffer
        #pragma unroll
        for (int mt = 0; mt < 4; ++mt) {
            #pragma unroll
            for (int r = 0; r < 4; ++r) {
                float iv = acc[0][mt][r];
                float fv = acc[1][mt][r];
                float gv = acc[2][mt][r];
                float ov = acc[3][mt][r];
                float cn = sigm(fv) * cst[s][mt][r] + sigm(iv) * tanh_(gv);
                cst[s][mt][r] = cn;
                float hv = sigm(ov) * tanh_(cn);
                Hout[hbase + (mt * 16 + r) * 260 + s * 16] = f2bf(hv);
            }
        }
    }
    __syncthreads();  // new h visible to next cell
}

__global__ __launch_bounds__(512, 2) void lstm_fused(
    const float* __restrict__ x,
    const unsigned short* __restrict__ pWC,
    const unsigned short* __restrict__ pWih1,
    const unsigned short* __restrict__ pWhh1,
    const unsigned short* __restrict__ pWih2,
    const unsigned short* __restrict__ pWhh2,
    const unsigned short* __restrict__ pWdec,
    const float* __restrict__ gb1a, const float* __restrict__ gb1b,
    const float* __restrict__ gb2, const float* __restrict__ gbd,
    float* __restrict__ out) {
    extern __shared__ unsigned char smem[];
    // double-buffered h (stride 260 shorts), + shared xbuf/dOut scratch
    unsigned short* h1[2]; unsigned short* h2[2];
    h1[0] = (unsigned short*)smem;          // 33280 B
    h1[1] = h1[0] + 64 * 260;
    h2[0] = h1[1] + 64 * 260;
    h2[1] = h2[0] + 64 * 260;
    unsigned short* xbuf = h2[1] + 64 * 260;   // 64×68 bf16 (cols 34..67 zero) = 8704 B
    float* dOut = (float*)xbuf;                // 64×48 f32 = 12288 B (aliases xbuf, used t>=9)

    const int tid = threadIdx.x;
    const int wave = tid >> 6;
    const int lane = tid & 63;
    const int ln15 = lane & 15;
    const int quad = lane >> 4;
    const int m0 = blockIdx.x * 64;

    // zero the parity-0 h buffers and the scratch region
    for (int i = tid; i < 8320; i += 512) { ((int*)h1[0])[i] = 0; ((int*)h2[0])[i] = 0; }
    for (int i = tid; i < 3072; i += 512) ((int*)xbuf)[i] = 0;

    // biases -> registers (folded into accumulator init later)
    float b1a[2][4], b1b[2][4], b2[2][4];
    #pragma unroll
    for (int s = 0; s < 2; ++s) {
        int c = wave * 32 + s * 16 + ln15;
        #pragma unroll
        for (int g = 0; g < 4; ++g) {
            b1a[s][g] = gb1a[g * 256 + c];
            b1b[s][g] = gb1b[g * 256 + c];
            b2[s][g]  = gb2[g * 256 + c];
        }
    }
    const float bd = (wave < 3) ? gbd[wave * 16 + ln15] : 0.f;

    float c1[2][4][4], c2[2][4][4];
    #pragma unroll
    for (int s = 0; s < 2; ++s)
        #pragma unroll
        for (int mt = 0; mt < 4; ++mt)
            #pragma unroll
            for (int r = 0; r < 4; ++r) { c1[s][mt][r] = 0.f; c2[s][mt][r] = 0.f; }
    f32x4 dAcc[4];  // decoder cumsum accumulator (waves 0..2 only)

    __syncthreads();

    #pragma unroll 1
    for (int t = 0; t < 19; ++t) {
        const int rp = t & 1;        // read parity
        const int wp = rp ^ 1;       // write parity
        if (t < 10) {
            // stage x_t -> xbuf (bf16; cols 34..67 remain zero)
            for (int i = tid; i < 1088; i += 512) {
                int r = i / 17, p = i - r * 17;
                f32x2 v = *(const f32x2*)(x + (m0 + r) * 340 + t * 34 + p * 2);
                unsigned int lo = f2bf(v.x), hi = f2bf(v.y);
                *(unsigned int*)(xbuf + r * 68 + p * 2) = lo | (hi << 16);
            }
            __syncthreads();
            cell_step<2, 68>(xbuf, h1[rp], (const s16x8*)pWC, (const s16x8*)pWhh1,
                             b1a, c1, h1[wp], wave, lane, ln15, quad);
        } else {
            cell_step<8, 260>(h2[rp], h1[rp], (const s16x8*)pWih1, (const s16x8*)pWhh1,
                              b1b, c1, h1[wp], wave, lane, ln15, quad);
        }
        cell_step<8, 260>(h1[wp], h2[rp], (const s16x8*)pWih2, (const s16x8*)pWhh2,
                          b2, c2, h2[wp], wave, lane, ln15, quad);

        if (t >= 9) {
            const int tout = t - 9;
            if (wave < 3) {  // decoder: dec = h2 @ W_dec^T + b_dec ; cumsum; +x[:,9,:] at tout 0
                const s16x8* wd = (const s16x8*)pWdec + __builtin_amdgcn_readfirstlane(wave * 512);
                const unsigned short* hsrc = h2[wp];
                const int ad = ln15 * 260 + quad * 8;
                f32x4 d[4];
                #pragma unroll
                for (int mt = 0; mt < 4; ++mt) d[mt] = f32x4{0.f, 0.f, 0.f, 0.f};
                #pragma unroll
                for (int kk = 0; kk < 8; ++kk) {
                    s16x8 b = wd[lane + kk * 64];
                    #pragma unroll
                    for (int mt = 0; mt < 4; ++mt) {
                        s16x8 a = *(const s16x8*)(hsrc + ad + kk * 32 + mt * (16 * 260));
                        d[mt] = MFMA(a, b, d[mt]);
                    }
                }
                const int col = wave * 16 + ln15;
                const bool valid = (col < 34);
                #pragma unroll
                for (int mt = 0; mt < 4; ++mt) {
                    #pragma unroll
                    for (int r = 0; r < 4; ++r) {
                        const int rloc = mt * 16 + quad * 4 + r;
                        float v = d[mt][r] + bd;
                        if (tout == 0) {
                            float xr = valid ? __builtin_nontemporal_load(x + (m0 + rloc) * 340 + 306 + col) : 0.f;
                            dAcc[mt][r] = v + xr;
                        } else {
                            dAcc[mt][r] += v;
                        }
                        dOut[rloc * 48 + col] = dAcc[mt][r];
                    }
                }
            }
            __syncthreads();
            // contiguous per-row non-temporal stores
            for (int i = tid; i < 1088; i += 512) {
                int r = i / 17, p = i - r * 17;
                f32x2 v = *(const f32x2*)(dOut + r * 48 + p * 2);
                __builtin_nontemporal_store(v, (f32x2*)(out + (m0 + r) * 340 + tout * 34) + p);
            }
            // next writer of dOut/xbuf is >=2 cell barriers away — no barrier needed here
        }
    }
}

// ---------------- launch ----------------

extern "C" void kernel_launch(void* const* d_in, const int* in_sizes, int n_in,
                              void* d_out, int out_size, void* d_ws, size_t ws_size,
                              hipStream_t stream) {
    const float* x     = (const float*)d_in[0];
    const float* W_enc = (const float*)d_in[1];
    const float* b_enc = (const float*)d_in[2];
    const float* Wih1  = (const float*)d_in[3];
    const float* Whh1  = (const float*)d_in[4];
    const float* bih1  = (const float*)d_in[5];
    const float* bhh1  = (const float*)d_in[6];
    const float* Wih2  = (const float*)d_in[7];
    const float* Whh2  = (const float*)d_in[8];
    const float* bih2  = (const float*)d_in[9];
    const float* bhh2  = (const float*)d_in[10];
    const float* W_dec = (const float*)d_in[11];
    const float* b_dec = (const float*)d_in[12];
    float* out = (float*)d_out;

    unsigned char* w = (unsigned char*)d_ws;
    float* WC   = (float*)(w + 0);         // 139264
    float* benc = (float*)(w + 139264);    // 4096
    float* bs1a = (float*)(w + 143360);
    float* bs1b = (float*)(w + 147456);
    float* bs2  = (float*)(w + 151552);
    float* bdec = (float*)(w + 155648);    // 256
    unsigned short* pWC   = (unsigned short*)(w + 155904);   // 131072
    unsigned short* pWih1 = (unsigned short*)(w + 286976);   // 524288 each
    unsigned short* pWhh1 = (unsigned short*)(w + 811264);
    unsigned short* pWih2 = (unsigned short*)(w + 1335552);
    unsigned short* pWhh2 = (unsigned short*)(w + 1859840);
    unsigned short* pWdec = (unsigned short*)(w + 2384128);  // 24576

    wc_kernel<<<140, 256, 0, stream>>>(Wih1, W_enc, b_enc, WC, benc);
    pack_kernel<<<32, 256, 0, stream>>>(WC, pWC, 16, 2, 4, 256, 1024, 34);
    pack_kernel<<<128, 256, 0, stream>>>(Wih1, pWih1, 16, 8, 4, 256, 1024, 256);
    pack_kernel<<<128, 256, 0, stream>>>(Whh1, pWhh1, 16, 8, 4, 256, 1024, 256);
    pack_kernel<<<128, 256, 0, stream>>>(Wih2, pWih2, 16, 8, 4, 256, 1024, 256);
    pack_kernel<<<128, 256, 0, stream>>>(Whh2, pWhh2, 16, 8, 4, 256, 1024, 256);
    pack_kernel<<<6, 256, 0, stream>>>(W_dec, pWdec, 3, 8, 1, 0, 34, 256);
    bias_kernel<<<4, 256, 0, stream>>>(bih1, bhh1, benc, bih2, bhh2, b_dec, bs1a, bs1b, bs2, bdec);

    hipFuncSetAttribute((const void*)lstm_fused, hipFuncAttributeMaxDynamicSharedMemorySize, 145408);
    lstm_fused<<<256, 512, 145408, stream>>>(x, pWC, pWih1, pWhh1, pWih2, pWhh2, pWdec,
                                             bs1a, bs1b, bs2, bdec, out);
}

// Round 5
// 1188.855 us; speedup vs baseline: 1.5036x; 1.5036x over previous
//
#include <hip/hip_runtime.h>

typedef float f32x4 __attribute__((ext_vector_type(4)));
typedef float f32x2 __attribute__((ext_vector_type(2)));
typedef short s16x8 __attribute__((ext_vector_type(8)));
typedef __bf16 bf16x8 __attribute__((ext_vector_type(8)));

__device__ __forceinline__ unsigned short f2bf(float f) {
    unsigned int u = __builtin_bit_cast(unsigned int, f);
    u += 0x7FFFu + ((u >> 16) & 1u);
    return (unsigned short)(u >> 16);
}

__device__ __forceinline__ f32x4 MFMA(s16x8 a, s16x8 b, f32x4 c) {
    return __builtin_amdgcn_mfma_f32_16x16x32_bf16(
        __builtin_bit_cast(bf16x8, a), __builtin_bit_cast(bf16x8, b), c, 0, 0, 0);
}

__device__ __forceinline__ float sigm(float v) {
    return __builtin_amdgcn_rcpf(1.f + __builtin_amdgcn_exp2f(-1.4426950408889634f * v));
}
__device__ __forceinline__ float tanh_(float v) {
    return 2.f * __builtin_amdgcn_rcpf(1.f + __builtin_amdgcn_exp2f(-2.8853900817779268f * v)) - 1.f;
}

// ---------------- prologue kernels ----------------

__global__ void wc_kernel(const float* __restrict__ Wih1, const float* __restrict__ W_enc,
                          const float* __restrict__ b_enc, float* __restrict__ WC,
                          float* __restrict__ benc) {
    int i = blockIdx.x * 256 + threadIdx.x;
    if (i >= 1024 * 35) return;
    int j = i / 35;
    int f = i - j * 35;
    const float* wr = Wih1 + j * 256;
    float s = 0.f;
    if (f < 34) {
        for (int e = 0; e < 256; ++e) s += wr[e] * W_enc[e * 34 + f];
        WC[j * 34 + f] = s;
    } else {
        for (int e = 0; e < 256; ++e) s += wr[e] * b_enc[e];
        benc[j] = s;
    }
}

// Pack W (row-major [srcRows, srcK]) into per-wave-sequential bf16 B-frag streams:
// linear s16x8 index ((ntb*KK + kk)*G + g)*64 + lane holds
//   W[g*gStride + ntb*16 + (lane&15)][kk*32 + (lane>>4)*8 + j]  (0 outside bounds)
__global__ void pack_kernel(const float* __restrict__ src, unsigned short* __restrict__ dst,
                            int NTB, int KK, int G, int gStride, int srcRows, int srcK) {
    int idx = blockIdx.x * 256 + threadIdx.x;
    int total = NTB * KK * G * 64;
    if (idx >= total) return;
    int lane = idx & 63, q = idx >> 6;
    int g = q % G; q /= G;
    int kk = q % KK;
    int ntb = q / KK;
    int row = g * gStride + ntb * 16 + (lane & 15);
    int kbase = kk * 32 + ((lane >> 4) & 3) * 8;
    s16x8 v;
    #pragma unroll
    for (int j = 0; j < 8; ++j) {
        int k = kbase + j;
        float fv = (row < srcRows && k < srcK) ? src[row * srcK + k] : 0.f;
        v[j] = (short)f2bf(fv);
    }
    *(s16x8*)(dst + (long)idx * 8) = v;
}

__global__ void bias_kernel(const float* bih1, const float* bhh1, const float* benc,
                            const float* bih2, const float* bhh2, const float* b_dec,
                            float* bs1a, float* bs1b, float* bs2, float* bdec) {
    int j = blockIdx.x * 256 + threadIdx.x;
    if (j < 1024) {
        float s = bih1[j] + bhh1[j];
        bs1a[j] = s + benc[j];
        bs1b[j] = s;
        bs2[j] = bih2[j] + bhh2[j];
    }
    if (j < 48) bdec[j] = (j < 34) ? b_dec[j] : 0.f;
}

// ---------------- fused LSTM kernel ----------------

// One LSTM cell over this block's 64 rows. K-stream = input phase (KKIN ktiles of 32)
// then hidden phase (8 ktiles), depth-2 A/B register ping-pong, pair-loop kept at
// unroll 1 to bound live ranges (R4 lesson: full unroll => scratch spills => 3.4 GB
// HBM spill traffic). Biases live in LDS, folded into acc init. Single barrier/cell.
template<int KKIN, int SIN>
__device__ __forceinline__ void cell_step(
    const unsigned short* __restrict__ Ain,    // LDS, input-phase A, stride SIN shorts
    const unsigned short* __restrict__ Ahid,   // LDS, hidden-phase A, stride 260 shorts
    const s16x8* __restrict__ pWin,            // packed weights, KK=KKIN
    const s16x8* __restrict__ pWhid,           // packed weights, KK=8
    const float* __restrict__ Lbias,           // LDS, 1024 floats (i,f,g,o blocks)
    float (&cst)[2][4][4],
    unsigned short* __restrict__ Hout,         // LDS, stride 260 shorts (inactive buffer)
    int wave, int lane, int ln15, int quad)
{
    const int aIn   = ln15 * SIN + quad * 8;
    const int aHid  = ln15 * 260 + quad * 8;
    const int hbase = (quad * 4) * 260 + wave * 32 + ln15;
    #pragma unroll
    for (int s = 0; s < 2; ++s) {
        const int ntb = wave * 2 + s;
        const s16x8* wIn  = pWin  + __builtin_amdgcn_readfirstlane(ntb * (KKIN * 256));
        const s16x8* wHid = pWhid + __builtin_amdgcn_readfirstlane(ntb * 2048);
        const int colB = wave * 32 + s * 16 + ln15;
        f32x4 acc[4][4];
        #pragma unroll
        for (int g = 0; g < 4; ++g) {
            const float b = Lbias[g * 256 + colB];
            #pragma unroll
            for (int mt = 0; mt < 4; ++mt) acc[g][mt] = f32x4{b, b, b, b};
        }
        constexpr int TOT = KKIN + 8;  // even (10 or 16)
        s16x8 A0[4], A1[4], B0[4], B1[4];
        {   // u = 0 (always input phase)
            #pragma unroll
            for (int g = 0; g < 4; ++g) B0[g] = wIn[lane + g * 64];
            #pragma unroll
            for (int mt = 0; mt < 4; ++mt)
                A0[mt] = *(const s16x8*)(Ain + aIn + mt * (16 * SIN));
        }
        #pragma unroll 1
        for (int t = 0; t < TOT; t += 2) {
            {   // prefetch t+1 -> B1/A1 (branch-local compile-time strides)
                const int u = t + 1;
                if (u < KKIN) {
                    #pragma unroll
                    for (int g = 0; g < 4; ++g) B1[g] = wIn[lane + u * 256 + g * 64];
                    #pragma unroll
                    for (int mt = 0; mt < 4; ++mt)
                        A1[mt] = *(const s16x8*)(Ain + aIn + u * 32 + mt * (16 * SIN));
                } else {
                    const int vh = u - KKIN;
                    #pragma unroll
                    for (int g = 0; g < 4; ++g) B1[g] = wHid[lane + vh * 256 + g * 64];
                    #pragma unroll
                    for (int mt = 0; mt < 4; ++mt)
                        A1[mt] = *(const s16x8*)(Ahid + aHid + vh * 32 + mt * (16 * 260));
                }
            }
            #pragma unroll
            for (int g = 0; g < 4; ++g)
                #pragma unroll
                for (int mt = 0; mt < 4; ++mt) acc[g][mt] = MFMA(A0[mt], B0[g], acc[g][mt]);
            if (t + 2 < TOT) {  // prefetch t+2 -> B0/A0
                const int u = t + 2;
                if (u < KKIN) {
                    #pragma unroll
                    for (int g = 0; g < 4; ++g) B0[g] = wIn[lane + u * 256 + g * 64];
                    #pragma unroll
                    for (int mt = 0; mt < 4; ++mt)
                        A0[mt] = *(const s16x8*)(Ain + aIn + u * 32 + mt * (16 * SIN));
                } else {
                    const int vh = u - KKIN;
                    #pragma unroll
                    for (int g = 0; g < 4; ++g) B0[g] = wHid[lane + vh * 256 + g * 64];
                    #pragma unroll
                    for (int mt = 0; mt < 4; ++mt)
                        A0[mt] = *(const s16x8*)(Ahid + aHid + vh * 32 + mt * (16 * 260));
                }
            }
            #pragma unroll
            for (int g = 0; g < 4; ++g)
                #pragma unroll
                for (int mt = 0; mt < 4; ++mt) acc[g][mt] = MFMA(A1[mt], B1[g], acc[g][mt]);
        }
        // activations; write h straight to the inactive buffer
        #pragma unroll
        for (int mt = 0; mt < 4; ++mt) {
            #pragma unroll
            for (int r = 0; r < 4; ++r) {
                float iv = acc[0][mt][r];
                float fv = acc[1][mt][r];
                float gv = acc[2][mt][r];
                float ov = acc[3][mt][r];
                float cn = sigm(fv) * cst[s][mt][r] + sigm(iv) * tanh_(gv);
                cst[s][mt][r] = cn;
                float hv = sigm(ov) * tanh_(cn);
                Hout[hbase + (mt * 16 + r) * 260 + s * 16] = f2bf(hv);
            }
        }
    }
    __syncthreads();  // new h visible to next cell
}

__global__ __launch_bounds__(512, 2) void lstm_fused(
    const float* __restrict__ x,
    const unsigned short* __restrict__ pWC,
    const unsigned short* __restrict__ pWih1,
    const unsigned short* __restrict__ pWhh1,
    const unsigned short* __restrict__ pWih2,
    const unsigned short* __restrict__ pWhh2,
    const unsigned short* __restrict__ pWdec,
    const float* __restrict__ gb1a, const float* __restrict__ gb1b,
    const float* __restrict__ gb2, const float* __restrict__ gbd,
    float* __restrict__ out) {
    extern __shared__ unsigned char smem[];
    unsigned short* h1[2]; unsigned short* h2[2];
    h1[0] = (unsigned short*)smem;            // 4 × 33280 B (stride 260 shorts)
    h1[1] = h1[0] + 64 * 260;
    h2[0] = h1[1] + 64 * 260;
    h2[1] = h2[0] + 64 * 260;
    unsigned short* xbuf = h2[1] + 64 * 260;  // 64×68 bf16 (cols 34..67 zero), 8704 B
    float* dOut = (float*)xbuf;               // 64×48 f32 cumsum accum (aliases xbuf; safe:
                                              // staging ends at t=9 before first dOut write)
    float* Lb1a = (float*)((unsigned char*)smem + 145408);
    float* Lb1b = Lb1a + 1024;
    float* Lb2  = Lb1b + 1024;
    float* Lbd  = Lb2 + 1024;                 // 48 floats

    const int tid = threadIdx.x;
    const int wave = tid >> 6;
    const int lane = tid & 63;
    const int ln15 = lane & 15;
    const int quad = lane >> 4;
    const int m0 = blockIdx.x * 64;

    for (int i = tid; i < 8320; i += 512) { ((int*)h1[0])[i] = 0; ((int*)h2[0])[i] = 0; }
    for (int i = tid; i < 3072; i += 512) ((int*)xbuf)[i] = 0;
    for (int i = tid; i < 1024; i += 512) { Lb1a[i] = gb1a[i]; Lb1b[i] = gb1b[i]; Lb2[i] = gb2[i]; }
    if (tid < 48) Lbd[tid] = gbd[tid];

    float c1[2][4][4], c2[2][4][4];
    #pragma unroll
    for (int s = 0; s < 2; ++s)
        #pragma unroll
        for (int mt = 0; mt < 4; ++mt)
            #pragma unroll
            for (int r = 0; r < 4; ++r) { c1[s][mt][r] = 0.f; c2[s][mt][r] = 0.f; }

    __syncthreads();

    #pragma unroll 1
    for (int t = 0; t < 19; ++t) {
        const int rp = t & 1;        // read parity
        const int wp = rp ^ 1;       // write parity
        if (t < 10) {
            // stage x_t -> xbuf (bf16; cols 34..67 remain zero)
            for (int i = tid; i < 1088; i += 512) {
                int r = i / 17, p = i - r * 17;
                f32x2 v = __builtin_nontemporal_load((const f32x2*)(x + (m0 + r) * 340 + t * 34) + p);
                unsigned int lo = f2bf(v.x), hi = f2bf(v.y);
                *(unsigned int*)(xbuf + r * 68 + p * 2) = lo | (hi << 16);
            }
            __syncthreads();
            cell_step<2, 68>(xbuf, h1[rp], (const s16x8*)pWC, (const s16x8*)pWhh1,
                             Lb1a, c1, h1[wp], wave, lane, ln15, quad);
        } else {
            cell_step<8, 260>(h2[rp], h1[rp], (const s16x8*)pWih1, (const s16x8*)pWhh1,
                              Lb1b, c1, h1[wp], wave, lane, ln15, quad);
        }
        cell_step<8, 260>(h1[wp], h2[rp], (const s16x8*)pWih2, (const s16x8*)pWhh2,
                          Lb2, c2, h2[wp], wave, lane, ln15, quad);

        if (t >= 9) {
            const int tout = t - 9;
            if (wave < 3) {  // decoder: dec = h2 @ W_dec^T + b_dec; cumsum kept in dOut (LDS)
                const s16x8* wd = (const s16x8*)pWdec + __builtin_amdgcn_readfirstlane(wave * 512);
                const unsigned short* hsrc = h2[wp];
                const int ad = ln15 * 260 + quad * 8;
                f32x4 d[4];
                #pragma unroll
                for (int mt = 0; mt < 4; ++mt) d[mt] = f32x4{0.f, 0.f, 0.f, 0.f};
                #pragma unroll
                for (int kk = 0; kk < 8; ++kk) {
                    s16x8 b = wd[lane + kk * 64];
                    #pragma unroll
                    for (int mt = 0; mt < 4; ++mt) {
                        s16x8 a = *(const s16x8*)(hsrc + ad + kk * 32 + mt * (16 * 260));
                        d[mt] = MFMA(a, b, d[mt]);
                    }
                }
                const int col = wave * 16 + ln15;
                const bool valid = (col < 34);
                const float bd = Lbd[col];
                #pragma unroll
                for (int mt = 0; mt < 4; ++mt) {
                    #pragma unroll
                    for (int r = 0; r < 4; ++r) {
                        const int rloc = mt * 16 + quad * 4 + r;
                        float v = d[mt][r] + bd;
                        if (tout == 0) {
                            float xr = valid ? __builtin_nontemporal_load(x + (m0 + rloc) * 340 + 306 + col) : 0.f;
                            dOut[rloc * 48 + col] = v + xr;
                        } else {
                            dOut[rloc * 48 + col] += v;
                        }
                    }
                }
            }
            __syncthreads();
            // contiguous per-row non-temporal stores (cols 0..33 only)
            for (int i = tid; i < 1088; i += 512) {
                int r = i / 17, p = i - r * 17;
                f32x2 v = *(const f32x2*)(dOut + r * 48 + p * 2);
                __builtin_nontemporal_store(v, (f32x2*)(out + (m0 + r) * 340 + tout * 34) + p);
            }
            // next writer of dOut is >=2 cell barriers away — no barrier needed here
        }
    }
}

// ---------------- launch ----------------

extern "C" void kernel_launch(void* const* d_in, const int* in_sizes, int n_in,
                              void* d_out, int out_size, void* d_ws, size_t ws_size,
                              hipStream_t stream) {
    const float* x     = (const float*)d_in[0];
    const float* W_enc = (const float*)d_in[1];
    const float* b_enc = (const float*)d_in[2];
    const float* Wih1  = (const float*)d_in[3];
    const float* Whh1  = (const float*)d_in[4];
    const float* bih1  = (const float*)d_in[5];
    const float* bhh1  = (const float*)d_in[6];
    const float* Wih2  = (const float*)d_in[7];
    const float* Whh2  = (const float*)d_in[8];
    const float* bih2  = (const float*)d_in[9];
    const float* bhh2  = (const float*)d_in[10];
    const float* W_dec = (const float*)d_in[11];
    const float* b_dec = (const float*)d_in[12];
    float* out = (float*)d_out;

    unsigned char* w = (unsigned char*)d_ws;
    float* WC   = (float*)(w + 0);         // 139264
    float* benc = (float*)(w + 139264);    // 4096
    float* bs1a = (float*)(w + 143360);
    float* bs1b = (float*)(w + 147456);
    float* bs2  = (float*)(w + 151552);
    float* bdec = (float*)(w + 155648);    // 256
    unsigned short* pWC   = (unsigned short*)(w + 155904);   // 131072
    unsigned short* pWih1 = (unsigned short*)(w + 286976);   // 524288 each
    unsigned short* pWhh1 = (unsigned short*)(w + 811264);
    unsigned short* pWih2 = (unsigned short*)(w + 1335552);
    unsigned short* pWhh2 = (unsigned short*)(w + 1859840);
    unsigned short* pWdec = (unsigned short*)(w + 2384128);  // 24576

    wc_kernel<<<140, 256, 0, stream>>>(Wih1, W_enc, b_enc, WC, benc);
    pack_kernel<<<32, 256, 0, stream>>>(WC, pWC, 16, 2, 4, 256, 1024, 34);
    pack_kernel<<<128, 256, 0, stream>>>(Wih1, pWih1, 16, 8, 4, 256, 1024, 256);
    pack_kernel<<<128, 256, 0, stream>>>(Whh1, pWhh1, 16, 8, 4, 256, 1024, 256);
    pack_kernel<<<128, 256, 0, stream>>>(Wih2, pWih2, 16, 8, 4, 256, 1024, 256);
    pack_kernel<<<128, 256, 0, stream>>>(Whh2, pWhh2, 16, 8, 4, 256, 1024, 256);
    pack_kernel<<<6, 256, 0, stream>>>(W_dec, pWdec, 3, 8, 1, 0, 34, 256);
    bias_kernel<<<4, 256, 0, stream>>>(bih1, bhh1, benc, bih2, bhh2, b_dec, bs1a, bs1b, bs2, bdec);

    // LDS: 4×33280 (h dbuf) + 12288 (xbuf/dOut) + 3×4096 (biases) + 192 (bdec) = 157888 B
    hipFuncSetAttribute((const void*)lstm_fused, hipFuncAttributeMaxDynamicSharedMemorySize, 157888);
    lstm_fused<<<256, 512, 157888, stream>>>(x, pWC, pWih1, pWhh1, pWih2, pWhh2, pWdec,
                                             bs1a, bs1b, bs2, bdec, out);
}